// Round 15
// baseline (192.592 us; speedup 1.0000x reference)
//
#include <hip/hip_runtime.h>

// MultiHeadAttention: B=2, S=2048, D=1024, H=16, hd=64. fp32 I/O.
// Round 15: attention CU-load-balance permutation. Block p stages 32-p
// k-tiles (17..32) but computes a constant 33 tiles; with 2 blocks/CU the
// worst CU carried ~64 stage-units vs mean 49. p is now drawn from a
// permutation balanced under BOTH plausible block->CU mappings
// (consecutive pairs AND +256 strided): zig-zag in x, reflected in bh.
// Everything else identical to R14 (191.0us best).

typedef __attribute__((ext_vector_type(8))) short short8;
typedef __attribute__((ext_vector_type(4))) float floatx4;

__device__ inline unsigned short f2bf(float f) {
  unsigned u = __float_as_uint(f);
  unsigned r = (u + 0x7fffu + ((u >> 16) & 1u)) >> 16;  // RNE
  return (unsigned short)r;
}

__device__ __forceinline__ float fast_exp2(float x) {
#if __has_builtin(__builtin_amdgcn_exp2f)
  return __builtin_amdgcn_exp2f(x);
#else
  float r;
  asm volatile("v_exp_f32_e32 %0, %1" : "=v"(r) : "v"(x));
  return r;
#endif
}

__device__ __forceinline__ void gll16(const unsigned short* g, unsigned short* l) {
  __builtin_amdgcn_global_load_lds(
      (const __attribute__((address_space(1))) unsigned int*)(g),
      (__attribute__((address_space(3))) unsigned int*)(l),
      16, 0, 0);
}

constexpr int B_ = 2, S_ = 2048, D_ = 1024, H_ = 16, HD_ = 64;

// ---------------------------------------------------------------------------
// Merged one-time converter: z=0..3 -> W transpose+convert; z=4 -> X convert.
// ---------------------------------------------------------------------------
__global__ __launch_bounds__(256) void prep_inputs(
    const float* __restrict__ x, unsigned short* __restrict__ xb,
    const float* __restrict__ w0, const float* __restrict__ w1,
    const float* __restrict__ w2, const float* __restrict__ w3,
    unsigned short* __restrict__ wt_base)
{
  if (blockIdx.z == 4) {
    const int tid = threadIdx.y * 32 + threadIdx.x;
    const size_t base =
        ((size_t)(blockIdx.y * 32 + blockIdx.x) * 256 + tid) * 16;
#pragma unroll
    for (int half = 0; half < 2; ++half) {
      const size_t i = base + half * 8;
      float4 a = *(const float4*)(x + i);
      float4 b = *(const float4*)(x + i + 4);
      short8 o;
      o[0] = (short)f2bf(a.x); o[1] = (short)f2bf(a.y);
      o[2] = (short)f2bf(a.z); o[3] = (short)f2bf(a.w);
      o[4] = (short)f2bf(b.x); o[5] = (short)f2bf(b.y);
      o[6] = (short)f2bf(b.z); o[7] = (short)f2bf(b.w);
      *(short8*)(xb + i) = o;
    }
    return;
  }
  const float* src;
  switch (blockIdx.z) {
    case 0: src = w0; break;
    case 1: src = w1; break;
    case 2: src = w2; break;
    default: src = w3; break;
  }
  unsigned short* dst = wt_base + (size_t)blockIdx.z * 1024 * 1024;
  __shared__ unsigned short t[32][33];
  const int bx = blockIdx.x * 32;  // n
  const int by = blockIdx.y * 32;  // k
  const int x_ = threadIdx.x;
  for (int yy = threadIdx.y; yy < 32; yy += 8)
    t[yy][x_] = f2bf(src[(size_t)(by + yy) * 1024 + bx + x_]);
  __syncthreads();
  for (int yy = threadIdx.y; yy < 32; yy += 8)
    dst[(size_t)(bx + yy) * 1024 + by + x_] = t[x_][yy];
}

// Vb[b][s][h*64+d] bf16 -> Vt[(b*16+h)*64+d][s] bf16
__global__ __launch_bounds__(256) void transpose_v(
    const unsigned short* __restrict__ Vb, unsigned short* __restrict__ Vt)
{
  __shared__ unsigned short t[32][33];
  const int bh = blockIdx.z;
  const int b = bh >> 4, h = bh & 15;
  const int s0 = blockIdx.x * 32, d0 = blockIdx.y * 32;
  const int x = threadIdx.x;
  for (int yy = threadIdx.y; yy < 32; yy += 8)
    t[yy][x] = Vb[(size_t)(b * 2048 + s0 + yy) * 1024 + h * 64 + d0 + x];
  __syncthreads();
  for (int yy = threadIdx.y; yy < 32; yy += 8)
    Vt[((size_t)bh * 64 + d0 + yy) * 2048 + s0 + x] = t[x][yy];
}

// ---------------------------------------------------------------------------
// QKV GEMM (R11/R13, VGPR ~130): 128x128 tile, BK=64 two-subtile staging.
// ---------------------------------------------------------------------------
__global__ __launch_bounds__(256) void gemm256_qkv(
    const unsigned short* __restrict__ A,
    const unsigned short* __restrict__ Bt,
    unsigned short* __restrict__ Qo,
    unsigned short* __restrict__ Ko,
    unsigned short* __restrict__ Vo)
{
  __shared__ unsigned short sA[2][128 * 32];
  __shared__ unsigned short sB[2][128 * 32];
  const int K = 1024;
  const int m0 = blockIdx.y * 128;
  const int bn0 = blockIdx.x * 128;

  const int tid = threadIdx.x, wave = tid >> 6, lane = tid & 63;
  const int g = lane >> 4, ml = lane & 15;
  const int wm = wave & 1, wn = wave >> 1;

  const unsigned short* ag0 = A + (size_t)(m0 + (tid >> 2)) * K + (tid & 3) * 8;
  const unsigned short* ag1 = ag0 + (size_t)64 * K;
  const unsigned short* bg0 = Bt + (size_t)(bn0 + (tid >> 2)) * K + (tid & 3) * 8;
  const unsigned short* bg1 = bg0 + (size_t)64 * K;
  const int woff = wave * 512;

  floatx4 acc[4][4];
#pragma unroll
  for (int mt = 0; mt < 4; ++mt)
#pragma unroll
    for (int nt = 0; nt < 4; ++nt) acc[mt][nt] = (floatx4){0.f, 0.f, 0.f, 0.f};

  for (int k0 = 0; k0 < K; k0 += 64) {
    __syncthreads();
#pragma unroll
    for (int t = 0; t < 2; ++t) {
      gll16(ag0 + k0 + t * 32, sA[t] + woff);
      gll16(ag1 + k0 + t * 32, sA[t] + 2048 + woff);
      gll16(bg0 + k0 + t * 32, sB[t] + woff);
      gll16(bg1 + k0 + t * 32, sB[t] + 2048 + woff);
    }
    __syncthreads();
#pragma unroll
    for (int t = 0; t < 2; ++t) {
      short8 af[4], bf[4];
#pragma unroll
      for (int mt = 0; mt < 4; ++mt)
        af[mt] = *(const short8*)(sA[t] + (wm * 64 + mt * 16 + ml) * 32 + g * 8);
#pragma unroll
      for (int nt = 0; nt < 4; ++nt)
        bf[nt] = *(const short8*)(sB[t] + (wn * 64 + nt * 16 + ml) * 32 + g * 8);
#pragma unroll
      for (int mt = 0; mt < 4; ++mt)
#pragma unroll
        for (int nt = 0; nt < 4; ++nt)
          acc[mt][nt] = __builtin_amdgcn_mfma_f32_16x16x32_bf16(
              af[mt], bf[nt], acc[mt][nt], 0, 0, 0);
    }
  }

  const int proj = blockIdx.x >> 3;
  unsigned short* out = (proj == 0) ? Qo : (proj == 1) ? Ko : Vo;
  const int col0 = (blockIdx.x & 7) * 128;
#pragma unroll
  for (int mt = 0; mt < 4; ++mt) {
#pragma unroll
    for (int nt = 0; nt < 4; ++nt) {
      const int col = col0 + wn * 64 + nt * 16 + ml;
#pragma unroll
      for (int r = 0; r < 4; ++r) {
        const int row = m0 + wm * 64 + mt * 16 + g * 4 + r;
        out[(size_t)row * 1024 + col] = f2bf(acc[mt][nt][r]);
      }
    }
  }
}

// Output projection, 64x128 tile, BK=64 two-subtile staging (unchanged).
__global__ __launch_bounds__(256) void gemm_wo64(
    const unsigned short* __restrict__ A,
    const unsigned short* __restrict__ Bt,
    const float* __restrict__ bias,
    float* __restrict__ C)
{
  __shared__ unsigned short sA[2][64 * 32];
  __shared__ unsigned short sB[2][128 * 32];
  const int K = 1024;
  const int m0 = blockIdx.y * 64;
  const int bn0 = blockIdx.x * 128;
  const int tid = threadIdx.x, wave = tid >> 6, lane = tid & 63;
  const int g = lane >> 4, ml = lane & 15;
  const int wm = wave & 1, wn = wave >> 1;

  const unsigned short* ag =
      A + (size_t)(m0 + wave * 16 + (lane >> 2)) * K + (lane & 3) * 8;
  const unsigned short* bg0 = Bt + (size_t)(bn0 + (tid >> 2)) * K + (tid & 3) * 8;
  const unsigned short* bg1 = bg0 + (size_t)64 * K;
  const int woff = wave * 512;

  floatx4 acc[2][4];
#pragma unroll
  for (int mt = 0; mt < 2; ++mt)
#pragma unroll
    for (int nt = 0; nt < 4; ++nt) acc[mt][nt] = (floatx4){0.f, 0.f, 0.f, 0.f};

  for (int k0 = 0; k0 < K; k0 += 64) {
    __syncthreads();
#pragma unroll
    for (int t = 0; t < 2; ++t) {
      gll16(ag + k0 + t * 32, sA[t] + woff);
      gll16(bg0 + k0 + t * 32, sB[t] + woff);
      gll16(bg1 + k0 + t * 32, sB[t] + 2048 + woff);
    }
    __syncthreads();
#pragma unroll
    for (int t = 0; t < 2; ++t) {
      short8 af[2], bf[4];
#pragma unroll
      for (int mt = 0; mt < 2; ++mt)
        af[mt] = *(const short8*)(sA[t] + (wm * 32 + mt * 16 + ml) * 32 + g * 8);
#pragma unroll
      for (int nt = 0; nt < 4; ++nt)
        bf[nt] = *(const short8*)(sB[t] + (wn * 64 + nt * 16 + ml) * 32 + g * 8);
#pragma unroll
      for (int mt = 0; mt < 2; ++mt)
#pragma unroll
        for (int nt = 0; nt < 4; ++nt)
          acc[mt][nt] = __builtin_amdgcn_mfma_f32_16x16x32_bf16(
              af[mt], bf[nt], acc[mt][nt], 0, 0, 0);
    }
  }

#pragma unroll
  for (int mt = 0; mt < 2; ++mt) {
#pragma unroll
    for (int nt = 0; nt < 4; ++nt) {
      const int col = bn0 + wn * 64 + nt * 16 + ml;
      const float badd = bias[col];
#pragma unroll
      for (int r = 0; r < 4; ++r) {
        const int row = m0 + wm * 32 + mt * 16 + g * 4 + r;
        C[(size_t)row * 1024 + col] = acc[mt][nt][r] + badd;
      }
    }
  }
}

// ---------------------------------------------------------------------------
// Attention v9: = v8 (paired q-blocks, 2 k-tiles/barrier, raw-v_exp
// truncated-P softmax) + CU-load-balance permutation of p.
// ---------------------------------------------------------------------------
constexpr int LDP = 72;

__device__ __forceinline__ void attn_tile(
    const short8* aq,
    const unsigned short* sK0, const unsigned short* sK1,
    const unsigned short* sV0, const unsigned short* sV1,
    unsigned short* pw, floatx4* acc, float* l,
    const bool diag, const int qrow0, const int kcol0,
    const int g, const int ml)
{
  const float C1 = 0.18033688f;    // 0.125 / ln2
  const float C2 = -34.6246810f;   // -24 / ln2

  floatx4 s[4];
#pragma unroll
  for (int nb = 0; nb < 4; ++nb) {
    s[nb] = (floatx4){0.f, 0.f, 0.f, 0.f};
    short8 bk0 = *(const short8*)(sK0 + (nb * 16 + ml) * 32 + g * 8);
    s[nb] = __builtin_amdgcn_mfma_f32_16x16x32_bf16(aq[0], bk0, s[nb], 0, 0, 0);
    short8 bk1 = *(const short8*)(sK1 + (nb * 16 + ml) * 32 + g * 8);
    s[nb] = __builtin_amdgcn_mfma_f32_16x16x32_bf16(aq[1], bk1, s[nb], 0, 0, 0);
  }
#pragma unroll
  for (int r = 0; r < 4; ++r) {
    const int qrow = qrow0 + g * 4 + r;
    float rowsum = 0.f;
#pragma unroll
    for (int nb = 0; nb < 4; ++nb) {
      float wv = fast_exp2(fmaf(s[nb][r], C1, C2));
      if (diag && (kcol0 + nb * 16 + ml > qrow)) wv = 0.f;
      const unsigned bits = __float_as_uint(wv);
      pw[(g * 4 + r) * LDP + nb * 16 + ml] = (unsigned short)(bits >> 16);
      rowsum += __uint_as_float(bits & 0xffff0000u);
    }
    l[r] += rowsum;
  }
#pragma unroll
  for (int st = 0; st < 2; ++st) {
    short8 ap = *(const short8*)(pw + ml * LDP + st * 32 + g * 8);
    const unsigned short* sv = st ? sV1 : sV0;
#pragma unroll
    for (int jd = 0; jd < 4; ++jd) {
      short8 bv = *(const short8*)(sv + (jd * 16 + ml) * 32 + g * 8);
      acc[jd] = __builtin_amdgcn_mfma_f32_16x16x32_bf16(ap, bv, acc[jd], 0, 0, 0);
    }
  }
}

__global__ __launch_bounds__(256) void attn_v9(
    const unsigned short* __restrict__ Q,
    const unsigned short* __restrict__ Kg,
    const unsigned short* __restrict__ Vt,
    unsigned short* __restrict__ CTX)
{
  __shared__ unsigned short sK0[2][64 * 32], sK1[2][64 * 32];
  __shared__ unsigned short sV0[2][64 * 32], sV1[2][64 * 32];
  __shared__ unsigned short sP[4 * 16 * LDP];

  const int bh = blockIdx.y;
  const int b = bh >> 4, h = bh & 15;
  // CU-balance permutation: zig-zag in x, reflected for the upper bh half.
  // Consecutive-pair mapping: p(x)+p(x+1)=15 (even x). Strided (+256)
  // mapping: p(x,bh)+p(x,bh+16)=15. Both give ~49 stage-units per CU.
  const int x = blockIdx.x;
  const int zig = (x & 1) ? (15 - (x >> 1)) : (x >> 1);
  const int p = (bh < 16) ? zig : 15 - zig;
  const int qbA = p, qbB = 31 - p;
  const int qA0 = qbA * 64, qB0 = qbB * 64;
  const int tid = threadIdx.x, wave = tid >> 6, lane = tid & 63;
  const int g = lane >> 4, ml = lane & 15;

  const size_t headoff = (size_t)b * S_ * D_ + (size_t)h * HD_;
  const size_t vtoff   = (size_t)bh * HD_ * S_;

  short8 aqA[2], aqB[2];
  {
    const unsigned short* qp =
        Q + headoff + (size_t)(qA0 + wave * 16 + ml) * D_ + g * 8;
    aqA[0] = *(const short8*)qp;
    aqA[1] = *(const short8*)(qp + 32);
  }
  {
    const unsigned short* qp =
        Q + headoff + (size_t)(qB0 + wave * 16 + ml) * D_ + g * 8;
    aqB[0] = *(const short8*)qp;
    aqB[1] = *(const short8*)(qp + 32);
  }

  floatx4 accA[4], accB[4];
#pragma unroll
  for (int jd = 0; jd < 4; ++jd) {
    accA[jd] = (floatx4){0.f, 0.f, 0.f, 0.f};
    accB[jd] = (floatx4){0.f, 0.f, 0.f, 0.f};
  }
  float lA[4] = {0.f, 0.f, 0.f, 0.f};
  float lB[4] = {0.f, 0.f, 0.f, 0.f};

  const unsigned short* kgb =
      Kg + headoff + (size_t)(wave * 16 + (lane >> 2)) * D_ + (lane & 3) * 8;
  const unsigned short* vgb =
      Vt + vtoff + (size_t)(wave * 16 + (lane >> 2)) * S_ + (lane & 3) * 8;
  unsigned short* pw = sP + wave * 16 * LDP;
  const int woff = wave * 512;

  for (int kt0 = 0; kt0 <= qbB; kt0 += 2) {
    const bool two = (kt0 + 1 <= qbB);   // block-uniform
    __syncthreads();
#pragma unroll
    for (int t = 0; t < 2; ++t) {
      if (t == 1 && !two) break;
      const int kt = kt0 + t;
      const size_t ko = (size_t)kt * 64 * D_;
      gll16(kgb + ko,      sK0[t] + woff);
      gll16(kgb + ko + 32, sK1[t] + woff);
      gll16(vgb + kt * 64,      sV0[t] + woff);
      gll16(vgb + kt * 64 + 32, sV1[t] + woff);
    }
    __syncthreads();

#pragma unroll
    for (int t = 0; t < 2; ++t) {
      if (t == 1 && !two) break;
      const int kt = kt0 + t;
      attn_tile(aqB, sK0[t], sK1[t], sV0[t], sV1[t], pw, accB, lB,
                kt == qbB, qB0 + wave * 16, kt * 64, g, ml);
    }
#pragma unroll
    for (int t = 0; t < 2; ++t) {
      if (t == 1 && !two) break;
      const int kt = kt0 + t;
      if (kt <= qbA)
        attn_tile(aqA, sK0[t], sK1[t], sV0[t], sV1[t], pw, accA, lA,
                  kt == qbA, qA0 + wave * 16, kt * 64, g, ml);
    }
  }

#pragma unroll
  for (int r = 0; r < 4; ++r) {
    float la = lA[r];
    la += __shfl_xor(la, 1); la += __shfl_xor(la, 2);
    la += __shfl_xor(la, 4); la += __shfl_xor(la, 8);
    lA[r] = 1.0f / la;
    float lb = lB[r];
    lb += __shfl_xor(lb, 1); lb += __shfl_xor(lb, 2);
    lb += __shfl_xor(lb, 4); lb += __shfl_xor(lb, 8);
    lB[r] = 1.0f / lb;
  }
#pragma unroll
  for (int r = 0; r < 4; ++r) {
    const int rowA = qA0 + wave * 16 + g * 4 + r;
    const int rowB = qB0 + wave * 16 + g * 4 + r;
#pragma unroll
    for (int jd = 0; jd < 4; ++jd) {
      CTX[headoff + (size_t)rowA * D_ + jd * 16 + ml] = f2bf(accA[jd][r] * lA[r]);
      CTX[headoff + (size_t)rowB * D_ + jd * 16 + ml] = f2bf(accB[jd][r] * lB[r]);
    }
  }
}

// ---------------------------------------------------------------------------
extern "C" void kernel_launch(void* const* d_in, const int* in_sizes, int n_in,
                              void* d_out, int out_size, void* d_ws, size_t ws_size,
                              hipStream_t stream)
{
  const float* X  = (const float*)d_in[0];
  const float* Wq = (const float*)d_in[1];
  const float* Wk = (const float*)d_in[2];
  const float* Wv = (const float*)d_in[3];
  const float* Wo = (const float*)d_in[4];
  const float* bo = (const float*)d_in[5];

  char* ws = (char*)d_ws;
  const size_t MB = 1024 * 1024;

  unsigned short* Qb  = (unsigned short*)(ws);            // 8 MB (CTX aliases)
  unsigned short* Kb  = (unsigned short*)(ws + 8 * MB);   // 8 MB
  unsigned short* Xb  = (unsigned short*)(ws + 16 * MB);  // 8 MB; Vt after QKV
  unsigned short* WT  = (unsigned short*)(ws + 24 * MB);  // WqT|WkT|WvT|WoT
  unsigned short* WoT = WT + (size_t)3 * 1024 * 1024;
  unsigned short* Vb  = (unsigned short*)d_out;           // low 8MB of d_out
  unsigned short* Vt  = Xb;                               // reuse dead Xb

  // merged X-convert (z=4) + 4x W transpose/convert (z=0..3)
  prep_inputs<<<dim3(32, 32, 5), dim3(32, 8), 0, stream>>>(
      X, Xb, Wq, Wk, Wv, Wo, WT);
  // fused Q/K/V projection: Bt = WT[0..3071][1024], BK=64 staging
  gemm256_qkv<<<dim3(24, 32), 256, 0, stream>>>(Xb, WT, Qb, Kb, Vb);
  // V -> Vt[(b*16+h)*64+d][s]  (Xb dead now)
  transpose_v<<<dim3(64, 2, 32), dim3(32, 8), 0, stream>>>(Vb, Vt);
  // paired MFMA attention, 2 k-tiles/barrier, CU-balanced p; CTX aliases Q
  attn_v9<<<dim3(16, B_ * H_), 256, 0, stream>>>(Qb, Kb, Vt, Qb);
  // output projection + bias (64x128 tile, BK=64, 512 blocks)
  gemm_wo64<<<dim3(8, 64), 256, 0, stream>>>(Qb, WoT, bo, (float*)d_out);
}

// Round 16
// 190.764 us; speedup vs baseline: 1.0096x; 1.0096x over previous
//
#include <hip/hip_runtime.h>

// MultiHeadAttention: B=2, S=2048, D=1024, H=16, hd=64. fp32 I/O.
// Round 16: (1) attention stages THREE k-tiles per barrier (stages/bh
// 200 -> 132, 12 gll16 per drain; LDS 57.4KB, still 2 blocks/CU).
// (2) gemm_wo64 BK=128 four-subtile staging (8 stages vs 16; 48KB LDS,
// occupancy unchanged at 2 blocks/CU). R15's p-permutation dropped
// (measured neutral). Everything else = R14 (191.0us best).

typedef __attribute__((ext_vector_type(8))) short short8;
typedef __attribute__((ext_vector_type(4))) float floatx4;

__device__ inline unsigned short f2bf(float f) {
  unsigned u = __float_as_uint(f);
  unsigned r = (u + 0x7fffu + ((u >> 16) & 1u)) >> 16;  // RNE
  return (unsigned short)r;
}

__device__ __forceinline__ float fast_exp2(float x) {
#if __has_builtin(__builtin_amdgcn_exp2f)
  return __builtin_amdgcn_exp2f(x);
#else
  float r;
  asm volatile("v_exp_f32_e32 %0, %1" : "=v"(r) : "v"(x));
  return r;
#endif
}

__device__ __forceinline__ void gll16(const unsigned short* g, unsigned short* l) {
  __builtin_amdgcn_global_load_lds(
      (const __attribute__((address_space(1))) unsigned int*)(g),
      (__attribute__((address_space(3))) unsigned int*)(l),
      16, 0, 0);
}

constexpr int B_ = 2, S_ = 2048, D_ = 1024, H_ = 16, HD_ = 64;

// ---------------------------------------------------------------------------
// Merged one-time converter: z=0..3 -> W transpose+convert; z=4 -> X convert.
// ---------------------------------------------------------------------------
__global__ __launch_bounds__(256) void prep_inputs(
    const float* __restrict__ x, unsigned short* __restrict__ xb,
    const float* __restrict__ w0, const float* __restrict__ w1,
    const float* __restrict__ w2, const float* __restrict__ w3,
    unsigned short* __restrict__ wt_base)
{
  if (blockIdx.z == 4) {
    const int tid = threadIdx.y * 32 + threadIdx.x;
    const size_t base =
        ((size_t)(blockIdx.y * 32 + blockIdx.x) * 256 + tid) * 16;
#pragma unroll
    for (int half = 0; half < 2; ++half) {
      const size_t i = base + half * 8;
      float4 a = *(const float4*)(x + i);
      float4 b = *(const float4*)(x + i + 4);
      short8 o;
      o[0] = (short)f2bf(a.x); o[1] = (short)f2bf(a.y);
      o[2] = (short)f2bf(a.z); o[3] = (short)f2bf(a.w);
      o[4] = (short)f2bf(b.x); o[5] = (short)f2bf(b.y);
      o[6] = (short)f2bf(b.z); o[7] = (short)f2bf(b.w);
      *(short8*)(xb + i) = o;
    }
    return;
  }
  const float* src;
  switch (blockIdx.z) {
    case 0: src = w0; break;
    case 1: src = w1; break;
    case 2: src = w2; break;
    default: src = w3; break;
  }
  unsigned short* dst = wt_base + (size_t)blockIdx.z * 1024 * 1024;
  __shared__ unsigned short t[32][33];
  const int bx = blockIdx.x * 32;  // n
  const int by = blockIdx.y * 32;  // k
  const int x_ = threadIdx.x;
  for (int yy = threadIdx.y; yy < 32; yy += 8)
    t[yy][x_] = f2bf(src[(size_t)(by + yy) * 1024 + bx + x_]);
  __syncthreads();
  for (int yy = threadIdx.y; yy < 32; yy += 8)
    dst[(size_t)(bx + yy) * 1024 + by + x_] = t[x_][yy];
}

// Vb[b][s][h*64+d] bf16 -> Vt[(b*16+h)*64+d][s] bf16
__global__ __launch_bounds__(256) void transpose_v(
    const unsigned short* __restrict__ Vb, unsigned short* __restrict__ Vt)
{
  __shared__ unsigned short t[32][33];
  const int bh = blockIdx.z;
  const int b = bh >> 4, h = bh & 15;
  const int s0 = blockIdx.x * 32, d0 = blockIdx.y * 32;
  const int x = threadIdx.x;
  for (int yy = threadIdx.y; yy < 32; yy += 8)
    t[yy][x] = Vb[(size_t)(b * 2048 + s0 + yy) * 1024 + h * 64 + d0 + x];
  __syncthreads();
  for (int yy = threadIdx.y; yy < 32; yy += 8)
    Vt[((size_t)bh * 64 + d0 + yy) * 2048 + s0 + x] = t[x][yy];
}

// ---------------------------------------------------------------------------
// QKV GEMM (unchanged): 128x128 tile, BK=64 two-subtile staging.
// ---------------------------------------------------------------------------
__global__ __launch_bounds__(256) void gemm256_qkv(
    const unsigned short* __restrict__ A,
    const unsigned short* __restrict__ Bt,
    unsigned short* __restrict__ Qo,
    unsigned short* __restrict__ Ko,
    unsigned short* __restrict__ Vo)
{
  __shared__ unsigned short sA[2][128 * 32];
  __shared__ unsigned short sB[2][128 * 32];
  const int K = 1024;
  const int m0 = blockIdx.y * 128;
  const int bn0 = blockIdx.x * 128;

  const int tid = threadIdx.x, wave = tid >> 6, lane = tid & 63;
  const int g = lane >> 4, ml = lane & 15;
  const int wm = wave & 1, wn = wave >> 1;

  const unsigned short* ag0 = A + (size_t)(m0 + (tid >> 2)) * K + (tid & 3) * 8;
  const unsigned short* ag1 = ag0 + (size_t)64 * K;
  const unsigned short* bg0 = Bt + (size_t)(bn0 + (tid >> 2)) * K + (tid & 3) * 8;
  const unsigned short* bg1 = bg0 + (size_t)64 * K;
  const int woff = wave * 512;

  floatx4 acc[4][4];
#pragma unroll
  for (int mt = 0; mt < 4; ++mt)
#pragma unroll
    for (int nt = 0; nt < 4; ++nt) acc[mt][nt] = (floatx4){0.f, 0.f, 0.f, 0.f};

  for (int k0 = 0; k0 < K; k0 += 64) {
    __syncthreads();
#pragma unroll
    for (int t = 0; t < 2; ++t) {
      gll16(ag0 + k0 + t * 32, sA[t] + woff);
      gll16(ag1 + k0 + t * 32, sA[t] + 2048 + woff);
      gll16(bg0 + k0 + t * 32, sB[t] + woff);
      gll16(bg1 + k0 + t * 32, sB[t] + 2048 + woff);
    }
    __syncthreads();
#pragma unroll
    for (int t = 0; t < 2; ++t) {
      short8 af[4], bf[4];
#pragma unroll
      for (int mt = 0; mt < 4; ++mt)
        af[mt] = *(const short8*)(sA[t] + (wm * 64 + mt * 16 + ml) * 32 + g * 8);
#pragma unroll
      for (int nt = 0; nt < 4; ++nt)
        bf[nt] = *(const short8*)(sB[t] + (wn * 64 + nt * 16 + ml) * 32 + g * 8);
#pragma unroll
      for (int mt = 0; mt < 4; ++mt)
#pragma unroll
        for (int nt = 0; nt < 4; ++nt)
          acc[mt][nt] = __builtin_amdgcn_mfma_f32_16x16x32_bf16(
              af[mt], bf[nt], acc[mt][nt], 0, 0, 0);
    }
  }

  const int proj = blockIdx.x >> 3;
  unsigned short* out = (proj == 0) ? Qo : (proj == 1) ? Ko : Vo;
  const int col0 = (blockIdx.x & 7) * 128;
#pragma unroll
  for (int mt = 0; mt < 4; ++mt) {
#pragma unroll
    for (int nt = 0; nt < 4; ++nt) {
      const int col = col0 + wn * 64 + nt * 16 + ml;
#pragma unroll
      for (int r = 0; r < 4; ++r) {
        const int row = m0 + wm * 64 + mt * 16 + g * 4 + r;
        out[(size_t)row * 1024 + col] = f2bf(acc[mt][nt][r]);
      }
    }
  }
}

// Output projection, 64x128 tile, BK=128 four-subtile staging (8 stages).
__global__ __launch_bounds__(256) void gemm_wo64(
    const unsigned short* __restrict__ A,
    const unsigned short* __restrict__ Bt,
    const float* __restrict__ bias,
    float* __restrict__ C)
{
  __shared__ unsigned short sA[4][64 * 32];
  __shared__ unsigned short sB[4][128 * 32];
  const int K = 1024;
  const int m0 = blockIdx.y * 64;
  const int bn0 = blockIdx.x * 128;
  const int tid = threadIdx.x, wave = tid >> 6, lane = tid & 63;
  const int g = lane >> 4, ml = lane & 15;
  const int wm = wave & 1, wn = wave >> 1;

  const unsigned short* ag =
      A + (size_t)(m0 + wave * 16 + (lane >> 2)) * K + (lane & 3) * 8;
  const unsigned short* bg0 = Bt + (size_t)(bn0 + (tid >> 2)) * K + (tid & 3) * 8;
  const unsigned short* bg1 = bg0 + (size_t)64 * K;
  const int woff = wave * 512;

  floatx4 acc[2][4];
#pragma unroll
  for (int mt = 0; mt < 2; ++mt)
#pragma unroll
    for (int nt = 0; nt < 4; ++nt) acc[mt][nt] = (floatx4){0.f, 0.f, 0.f, 0.f};

  for (int k0 = 0; k0 < K; k0 += 128) {
    __syncthreads();
#pragma unroll
    for (int t = 0; t < 4; ++t) {
      gll16(ag + k0 + t * 32, sA[t] + woff);
      gll16(bg0 + k0 + t * 32, sB[t] + woff);
      gll16(bg1 + k0 + t * 32, sB[t] + 2048 + woff);
    }
    __syncthreads();
#pragma unroll
    for (int t = 0; t < 4; ++t) {
      short8 af[2], bf[4];
#pragma unroll
      for (int mt = 0; mt < 2; ++mt)
        af[mt] = *(const short8*)(sA[t] + (wm * 32 + mt * 16 + ml) * 32 + g * 8);
#pragma unroll
      for (int nt = 0; nt < 4; ++nt)
        bf[nt] = *(const short8*)(sB[t] + (wn * 64 + nt * 16 + ml) * 32 + g * 8);
#pragma unroll
      for (int mt = 0; mt < 2; ++mt)
#pragma unroll
        for (int nt = 0; nt < 4; ++nt)
          acc[mt][nt] = __builtin_amdgcn_mfma_f32_16x16x32_bf16(
              af[mt], bf[nt], acc[mt][nt], 0, 0, 0);
    }
  }

#pragma unroll
  for (int mt = 0; mt < 2; ++mt) {
#pragma unroll
    for (int nt = 0; nt < 4; ++nt) {
      const int col = bn0 + wn * 64 + nt * 16 + ml;
      const float badd = bias[col];
#pragma unroll
      for (int r = 0; r < 4; ++r) {
        const int row = m0 + wm * 32 + mt * 16 + g * 4 + r;
        C[(size_t)row * 1024 + col] = acc[mt][nt][r] + badd;
      }
    }
  }
}

// ---------------------------------------------------------------------------
// Attention v10: paired q-blocks {p, 31-p}, THREE k-tiles staged per barrier
// (stages/bh 200 -> 132; 12 gll16 per drain). Raw-v_exp truncated-P softmax.
// LDS 57.4 KB (still 2 blocks/CU at grid 512). sP wave-private, serial reuse.
// ---------------------------------------------------------------------------
constexpr int LDP = 72;
constexpr int KTPB = 3;  // k-tiles per barrier

__device__ __forceinline__ void attn_tile(
    const short8* aq,
    const unsigned short* sK0, const unsigned short* sK1,
    const unsigned short* sV0, const unsigned short* sV1,
    unsigned short* pw, floatx4* acc, float* l,
    const bool diag, const int qrow0, const int kcol0,
    const int g, const int ml)
{
  const float C1 = 0.18033688f;    // 0.125 / ln2
  const float C2 = -34.6246810f;   // -24 / ln2

  floatx4 s[4];
#pragma unroll
  for (int nb = 0; nb < 4; ++nb) {
    s[nb] = (floatx4){0.f, 0.f, 0.f, 0.f};
    short8 bk0 = *(const short8*)(sK0 + (nb * 16 + ml) * 32 + g * 8);
    s[nb] = __builtin_amdgcn_mfma_f32_16x16x32_bf16(aq[0], bk0, s[nb], 0, 0, 0);
    short8 bk1 = *(const short8*)(sK1 + (nb * 16 + ml) * 32 + g * 8);
    s[nb] = __builtin_amdgcn_mfma_f32_16x16x32_bf16(aq[1], bk1, s[nb], 0, 0, 0);
  }
#pragma unroll
  for (int r = 0; r < 4; ++r) {
    const int qrow = qrow0 + g * 4 + r;
    float rowsum = 0.f;
#pragma unroll
    for (int nb = 0; nb < 4; ++nb) {
      float wv = fast_exp2(fmaf(s[nb][r], C1, C2));
      if (diag && (kcol0 + nb * 16 + ml > qrow)) wv = 0.f;
      const unsigned bits = __float_as_uint(wv);
      pw[(g * 4 + r) * LDP + nb * 16 + ml] = (unsigned short)(bits >> 16);
      rowsum += __uint_as_float(bits & 0xffff0000u);
    }
    l[r] += rowsum;
  }
#pragma unroll
  for (int st = 0; st < 2; ++st) {
    short8 ap = *(const short8*)(pw + ml * LDP + st * 32 + g * 8);
    const unsigned short* sv = st ? sV1 : sV0;
#pragma unroll
    for (int jd = 0; jd < 4; ++jd) {
      short8 bv = *(const short8*)(sv + (jd * 16 + ml) * 32 + g * 8);
      acc[jd] = __builtin_amdgcn_mfma_f32_16x16x32_bf16(ap, bv, acc[jd], 0, 0, 0);
    }
  }
}

__global__ __launch_bounds__(256) void attn_v10(
    const unsigned short* __restrict__ Q,
    const unsigned short* __restrict__ Kg,
    const unsigned short* __restrict__ Vt,
    unsigned short* __restrict__ CTX)
{
  __shared__ unsigned short sK0[KTPB][64 * 32], sK1[KTPB][64 * 32];
  __shared__ unsigned short sV0[KTPB][64 * 32], sV1[KTPB][64 * 32];
  __shared__ unsigned short sP[4 * 16 * LDP];

  const int bh = blockIdx.y;
  const int b = bh >> 4, h = bh & 15;
  const int p = blockIdx.x;
  const int qbA = p, qbB = 31 - p;
  const int qA0 = qbA * 64, qB0 = qbB * 64;
  const int tid = threadIdx.x, wave = tid >> 6, lane = tid & 63;
  const int g = lane >> 4, ml = lane & 15;

  const size_t headoff = (size_t)b * S_ * D_ + (size_t)h * HD_;
  const size_t vtoff   = (size_t)bh * HD_ * S_;

  short8 aqA[2], aqB[2];
  {
    const unsigned short* qp =
        Q + headoff + (size_t)(qA0 + wave * 16 + ml) * D_ + g * 8;
    aqA[0] = *(const short8*)qp;
    aqA[1] = *(const short8*)(qp + 32);
  }
  {
    const unsigned short* qp =
        Q + headoff + (size_t)(qB0 + wave * 16 + ml) * D_ + g * 8;
    aqB[0] = *(const short8*)qp;
    aqB[1] = *(const short8*)(qp + 32);
  }

  floatx4 accA[4], accB[4];
#pragma unroll
  for (int jd = 0; jd < 4; ++jd) {
    accA[jd] = (floatx4){0.f, 0.f, 0.f, 0.f};
    accB[jd] = (floatx4){0.f, 0.f, 0.f, 0.f};
  }
  float lA[4] = {0.f, 0.f, 0.f, 0.f};
  float lB[4] = {0.f, 0.f, 0.f, 0.f};

  const unsigned short* kgb =
      Kg + headoff + (size_t)(wave * 16 + (lane >> 2)) * D_ + (lane & 3) * 8;
  const unsigned short* vgb =
      Vt + vtoff + (size_t)(wave * 16 + (lane >> 2)) * S_ + (lane & 3) * 8;
  unsigned short* pw = sP + wave * 16 * LDP;
  const int woff = wave * 512;

  const int ntiles = qbB + 1;
  for (int kt0 = 0; kt0 < ntiles; kt0 += KTPB) {
    const int cnt = (ntiles - kt0 < KTPB) ? (ntiles - kt0) : KTPB;  // uniform
    __syncthreads();
#pragma unroll
    for (int t = 0; t < KTPB; ++t) {
      if (t >= cnt) break;
      const int kt = kt0 + t;
      const size_t ko = (size_t)kt * 64 * D_;
      gll16(kgb + ko,      sK0[t] + woff);
      gll16(kgb + ko + 32, sK1[t] + woff);
      gll16(vgb + kt * 64,      sV0[t] + woff);
      gll16(vgb + kt * 64 + 32, sV1[t] + woff);
    }
    __syncthreads();

#pragma unroll
    for (int t = 0; t < KTPB; ++t) {
      if (t >= cnt) break;
      const int kt = kt0 + t;
      attn_tile(aqB, sK0[t], sK1[t], sV0[t], sV1[t], pw, accB, lB,
                kt == qbB, qB0 + wave * 16, kt * 64, g, ml);
    }
#pragma unroll
    for (int t = 0; t < KTPB; ++t) {
      if (t >= cnt) break;
      const int kt = kt0 + t;
      if (kt <= qbA)
        attn_tile(aqA, sK0[t], sK1[t], sV0[t], sV1[t], pw, accA, lA,
                  kt == qbA, qA0 + wave * 16, kt * 64, g, ml);
    }
  }

#pragma unroll
  for (int r = 0; r < 4; ++r) {
    float la = lA[r];
    la += __shfl_xor(la, 1); la += __shfl_xor(la, 2);
    la += __shfl_xor(la, 4); la += __shfl_xor(la, 8);
    lA[r] = 1.0f / la;
    float lb = lB[r];
    lb += __shfl_xor(lb, 1); lb += __shfl_xor(lb, 2);
    lb += __shfl_xor(lb, 4); lb += __shfl_xor(lb, 8);
    lB[r] = 1.0f / lb;
  }
#pragma unroll
  for (int r = 0; r < 4; ++r) {
    const int rowA = qA0 + wave * 16 + g * 4 + r;
    const int rowB = qB0 + wave * 16 + g * 4 + r;
#pragma unroll
    for (int jd = 0; jd < 4; ++jd) {
      CTX[headoff + (size_t)rowA * D_ + jd * 16 + ml] = f2bf(accA[jd][r] * lA[r]);
      CTX[headoff + (size_t)rowB * D_ + jd * 16 + ml] = f2bf(accB[jd][r] * lB[r]);
    }
  }
}

// ---------------------------------------------------------------------------
extern "C" void kernel_launch(void* const* d_in, const int* in_sizes, int n_in,
                              void* d_out, int out_size, void* d_ws, size_t ws_size,
                              hipStream_t stream)
{
  const float* X  = (const float*)d_in[0];
  const float* Wq = (const float*)d_in[1];
  const float* Wk = (const float*)d_in[2];
  const float* Wv = (const float*)d_in[3];
  const float* Wo = (const float*)d_in[4];
  const float* bo = (const float*)d_in[5];

  char* ws = (char*)d_ws;
  const size_t MB = 1024 * 1024;

  unsigned short* Qb  = (unsigned short*)(ws);            // 8 MB (CTX aliases)
  unsigned short* Kb  = (unsigned short*)(ws + 8 * MB);   // 8 MB
  unsigned short* Xb  = (unsigned short*)(ws + 16 * MB);  // 8 MB; Vt after QKV
  unsigned short* WT  = (unsigned short*)(ws + 24 * MB);  // WqT|WkT|WvT|WoT
  unsigned short* WoT = WT + (size_t)3 * 1024 * 1024;
  unsigned short* Vb  = (unsigned short*)d_out;           // low 8MB of d_out
  unsigned short* Vt  = Xb;                               // reuse dead Xb

  // merged X-convert (z=4) + 4x W transpose/convert (z=0..3)
  prep_inputs<<<dim3(32, 32, 5), dim3(32, 8), 0, stream>>>(
      X, Xb, Wq, Wk, Wv, Wo, WT);
  // fused Q/K/V projection: Bt = WT[0..3071][1024], BK=64 staging
  gemm256_qkv<<<dim3(24, 32), 256, 0, stream>>>(Xb, WT, Qb, Kb, Vb);
  // V -> Vt[(b*16+h)*64+d][s]  (Xb dead now)
  transpose_v<<<dim3(64, 2, 32), dim3(32, 8), 0, stream>>>(Vb, Vt);
  // paired MFMA attention, 3 k-tiles per barrier; CTX aliases Q
  attn_v10<<<dim3(16, B_ * H_), 256, 0, stream>>>(Qb, Kb, Vt, Qb);
  // output projection + bias (64x128 tile, BK=128, 512 blocks)
  gemm_wo64<<<dim3(8, 64), 256, 0, stream>>>(Qb, WoT, bo, (float*)d_out);
}